// Round 16
// baseline (76.255 us; speedup 1.0000x reference)
//
#include <hip/hip_runtime.h>
#include <math.h>

#define N_NODES 1000
#define T_STEPS 32
#define H_DIM   128
#define E_EDGES 16000
#define ED_DIM  16
#define G_GRAPHS 32
#define EP_EDGES (E_EDGES + N_NODES)
#define NEG_SLOPE 0.2f
#define LN_EPS 1e-5f
#define CSR_CAP 128

typedef __attribute__((ext_vector_type(8))) short bf16x8;
typedef __attribute__((ext_vector_type(16))) float f32x16;
typedef __attribute__((ext_vector_type(4))) float f32x4;
typedef __attribute__((ext_vector_type(4))) unsigned u32x4;
typedef unsigned short u16;

__device__ inline short f2bf(float f) {  // RNE f32 -> bf16
    unsigned u = __float_as_uint(f);
    u = (u + 0x7FFFu + ((u >> 16) & 1u)) >> 16;
    return (short)u;
}
__device__ inline float bf2f(u16 u) { return __uint_as_float(((unsigned)u) << 16); }
__device__ inline float bflo(unsigned u) { return __uint_as_float(u << 16); }
__device__ inline float bfhi(unsigned u) { return __uint_as_float(u & 0xFFFF0000u); }

// ---------- L1: pack weights only (80 blocks) ----------
__global__ __launch_bounds__(1024) void k_prep(
    const float* __restrict__ conv_w, const float* __restrict__ Wl,
    const float* __restrict__ Wr, short* __restrict__ wc, short* __restrict__ wg) {
    int i = blockIdx.x * 1024 + threadIdx.x;  // 0..81919
    if (i < 4 * 24 * 64 * 8) {
        int r = i & 7, lane = (i >> 3) & 63;
        int t = i >> 9;
        int kstep = t % 24, ct = t / 24;
        int k = kstep >> 3, hs = kstep & 7;
        int hi = hs * 16 + ((lane >> 5) << 3) + r;
        int o = ct * 32 + (lane & 31);
        wc[i] = f2bf(conv_w[(o * H_DIM + hi) * 3 + k]);
    } else {
        int j = i - 4 * 24 * 64 * 8;  // < 32768
        int r = j & 7, lane = (j >> 3) & 63;
        int ks = (j >> 9) & 7, ct = j >> 12;
        int hi = ks * 16 + ((lane >> 5) << 3) + r;
        int o = ct * 32 + (lane & 31);
        wg[j] = f2bf(o < H_DIM ? Wl[hi * H_DIM + o] : Wr[hi * H_DIM + o - H_DIM]);
    }
}

// ---------- L2 fused: temporal (0-999) | CSR build+sort+loop_attr+self-ee (1000-1999)
//            | edge ee x16 (2000-2999). Static LDS ~18.5KB -> 8 blocks/CU ----------
__global__ __launch_bounds__(256) void k_fuse(
    const float* __restrict__ x, const short* __restrict__ wc, const short* __restrict__ wg,
    const float* __restrict__ conv_b, const float* __restrict__ ln1_g,
    const float* __restrict__ ln1_b, const float* __restrict__ edge_attr,
    const float* __restrict__ We, const int* __restrict__ dst,
    int* __restrict__ csr, int* __restrict__ cnt,
    u16* __restrict__ x1b, u16* __restrict__ gl, u16* __restrict__ gr,
    u16* __restrict__ ee) {
    __shared__ __align__(16) short xb[34 * 136];   // 9248 B
    __shared__ __align__(16) u16 yb[32 * 136];     // 8704 B: conv-out bf16; reused as epilogue stage
    __shared__ int buf[CSR_CAP];
    __shared__ float laf[16];
    __shared__ int scnt;
    int b = blockIdx.x;
    int tid = threadIdx.x;

    if (b >= 2000) {  // ---- edge ee: 16 edges per block ----
        int e0 = (b - 2000) * 16 + (tid >> 7);
        int h = tid & 127;
#pragma unroll
        for (int k = 0; k < 16; k += 2) {
            int e = e0 + k;
            const float* ea = &edge_attr[e * ED_DIM];
            float acc = 0.f;
#pragma unroll
            for (int f = 0; f < ED_DIM; ++f) acc += ea[f] * We[f * H_DIM + h];
            __builtin_nontemporal_store((u16)f2bf(acc), &ee[(size_t)e * H_DIM + h]);
        }
        return;
    }
    if (b >= 1000) {  // ---- CSR build (scan dst) + sort + loop_attr + self-loop ee ----
        int n = b - 1000;
        if (tid == 0) scnt = 0;
        __syncthreads();
        const uint4* d4 = (const uint4*)dst;  // E_EDGES % 4 == 0
        for (int i = tid; i < E_EDGES / 4; i += 256) {
            uint4 v = d4[i];
            int e0 = i * 4;
            if ((int)v.x == n) { int s = atomicAdd(&scnt, 1); if (s < CSR_CAP) buf[s] = e0; }
            if ((int)v.y == n) { int s = atomicAdd(&scnt, 1); if (s < CSR_CAP) buf[s] = e0 + 1; }
            if ((int)v.z == n) { int s = atomicAdd(&scnt, 1); if (s < CSR_CAP) buf[s] = e0 + 2; }
            if ((int)v.w == n) { int s = atomicAdd(&scnt, 1); if (s < CSR_CAP) buf[s] = e0 + 3; }
        }
        __syncthreads();
        int deg = min(scnt, CSR_CAP);
        if (tid == 0) cnt[n] = deg;
        bool fast = (deg <= 64);
        if (fast) {
            if (tid < 64) {
                int v = (tid < deg) ? buf[tid] : 0x7FFFFFFF;
                int rank = 0;
#pragma unroll
                for (int j = 0; j < 64; ++j) {
                    int vj = __shfl(v, j);
                    rank += (vj < v) ? 1 : 0;
                }
                if (tid < deg) buf[rank] = v;
            }
        } else {
            if (tid == 0) {
                for (int i = 1; i < deg; ++i) {
                    int key = buf[i], j = i - 1;
                    while (j >= 0 && buf[j] > key) { buf[j + 1] = buf[j]; --j; }
                    buf[j + 1] = key;
                }
            }
        }
        __syncthreads();
        if (tid < deg) csr[n * CSR_CAP + tid] = buf[tid];
        if (tid < 64) {
            int q = tid >> 4, f = tid & 15;
            float a = 0.f;
            for (int i = q; i < deg; i += 4) a += edge_attr[buf[i] * ED_DIM + f];
            a += __shfl_xor(a, 16);
            a += __shfl_xor(a, 32);
            if (tid < 16) laf[tid] = a / fmaxf((float)deg, 1.0f);
        }
        __syncthreads();
        if (tid < H_DIM) {
            float acc = 0.f;
#pragma unroll
            for (int f = 0; f < ED_DIM; ++f) acc += laf[f] * We[f * H_DIM + tid];
            ee[(size_t)(E_EDGES + n) * H_DIM + tid] = (u16)f2bf(acc);
        }
        return;
    }

    // ---- temporal: conv (MFMA) + residual + LN1 + gl/gr (MFMA), bf16 outputs ----
    int n = b;
    int w = tid >> 6, lane = tid & 63;
    int arow = lane & 31;
    int aks = (lane >> 5) << 3;

    {
        const f32x4* xs4 = (const f32x4*)(x + (size_t)n * T_STEPS * H_DIM);
        for (int i4 = tid; i4 < T_STEPS * H_DIM / 4; i4 += 256) {
            f32x4 v = __builtin_nontemporal_load(&xs4[i4]);  // single-touch stream
            int t = i4 >> 5, h = (i4 * 4) & 127;
            uint2 pp;
            pp.x = (unsigned)(unsigned short)f2bf(v.x) | ((unsigned)(unsigned short)f2bf(v.y) << 16);
            pp.y = (unsigned)(unsigned short)f2bf(v.z) | ((unsigned)(unsigned short)f2bf(v.w) << 16);
            *(uint2*)&xb[(t + 1) * 136 + h] = pp;
        }
        if (tid < 68) {
            ((unsigned*)xb)[tid] = 0u;
            ((unsigned*)(xb + 33 * 136))[tid] = 0u;
        }
    }
    __syncthreads();

    f32x16 acc = {};
    for (int kk = 0; kk < 3; ++kk) {
#pragma unroll
        for (int hs = 0; hs < 8; ++hs) {
            int kstep = kk * 8 + hs;
            bf16x8 a = *(const bf16x8*)&xb[(arow + kk) * 136 + hs * 16 + aks];
            bf16x8 bb = *(const bf16x8*)&wc[((w * 24 + kstep) * 64 + lane) * 8];
            acc = __builtin_amdgcn_mfma_f32_32x32x16_bf16(a, bb, acc, 0, 0, 0);
        }
    }
    {
        int oc = w * 32 + (lane & 31);
        float cb = conv_b[oc];
#pragma unroll
        for (int r = 0; r < 16; ++r) {
            int t = (r & 3) + 8 * (r >> 2) + 4 * (lane >> 5);
            yb[t * 136 + oc] = (u16)f2bf(acc[r] + cb);  // bf16 staging (halves LDS)
        }
    }
    __syncthreads();

    // residual from bf16 x (xb halo rows) + bf16 conv-out + LN1; reg-stage (WAR across waves)
    float rr0[8], rr1[8];
#pragma unroll
    for (int idx = 0; idx < 8; ++idx) {
        int t = w + idx * 4;
        rr0[idx] = bf2f((u16)xb[(t + 1) * 136 + lane]) + bf2f(yb[t * 136 + lane]);
        rr1[idx] = bf2f((u16)xb[(t + 1) * 136 + lane + 64]) + bf2f(yb[t * 136 + lane + 64]);
    }
    __syncthreads();
    float g0c = ln1_g[lane], g1c = ln1_g[lane + 64];
    float b0c = ln1_b[lane], b1c = ln1_b[lane + 64];
#pragma unroll
    for (int idx = 0; idx < 8; ++idx) {
        int t = w + idx * 4;
        float r0 = rr0[idx], r1 = rr1[idx];
        float s = r0 + r1, s2 = r0 * r0 + r1 * r1;
#pragma unroll
        for (int mm = 1; mm < 64; mm <<= 1) {
            s += __shfl_xor(s, mm);
            s2 += __shfl_xor(s2, mm);
        }
        float mean = s * (1.f / 128.f);
        float var = s2 * (1.f / 128.f) - mean * mean;
        float rs = rsqrtf(var + LN_EPS);
        float o0 = (r0 - mean) * rs * g0c + b0c;
        float o1 = (r1 - mean) * rs * g1c + b1c;
        xb[t * 136 + lane] = f2bf(o0);
        xb[t * 136 + lane + 64] = f2bf(o1);
    }
    __syncthreads();

    for (int c = tid; c < 512; c += 256) {
        int t = c >> 4, p = c & 15;
        u32x4 v = *(const u32x4*)&xb[t * 136 + p * 8];
        *(u32x4*)&x1b[((size_t)n * T_STEPS + t) * H_DIM + p * 8] = v;
    }

    f32x16 cl = {}, cr = {};
#pragma unroll
    for (int ks = 0; ks < 8; ++ks) {
        bf16x8 a = *(const bf16x8*)&xb[arow * 136 + ks * 16 + aks];
        bf16x8 b0 = *(const bf16x8*)&wg[(((2 * w) * 8 + ks) * 64 + lane) * 8];
        bf16x8 b1 = *(const bf16x8*)&wg[(((2 * w + 1) * 8 + ks) * 64 + lane) * 8];
        cl = __builtin_amdgcn_mfma_f32_32x32x16_bf16(a, b0, cl, 0, 0, 0);
        cr = __builtin_amdgcn_mfma_f32_32x32x16_bf16(a, b1, cr, 0, 0, 0);
    }
    // two-pass epilogue staging (gl then gr) through the single 32x136 u16 buffer
    __syncthreads();  // all yb (conv) reads done
#pragma unroll
    for (int m = 0; m < 2; ++m) {
        if ((w >> 1) == m) {
            int c0 = (w & 1) * 64 + (lane & 31);
#pragma unroll
            for (int r = 0; r < 16; ++r) {
                int t = (r & 3) + 8 * (r >> 2) + 4 * (lane >> 5);
                yb[t * 136 + c0] = (u16)f2bf(cl[r]);
                yb[t * 136 + c0 + 32] = (u16)f2bf(cr[r]);
            }
        }
        __syncthreads();
        u16* d = m ? gr : gl;
        for (int c = tid; c < 512; c += 256) {
            int t = c >> 4, p = c & 15;
            u32x4 v = *(const u32x4*)&yb[t * 136 + p * 8];
            *(u32x4*)&d[((size_t)t * N_NODES + n) * H_DIM + p * 8] = v;
        }
        __syncthreads();
    }
}

// ---------- GATv2: block=(n, 8 graphs q+4j); 4-deep pipelined gather + defer-max ----------
__global__ __launch_bounds__(128) void k_gat(
    const u16* __restrict__ gl, const u16* __restrict__ gr, const u16* __restrict__ ee,
    const int* __restrict__ src_arr, const int* __restrict__ csr,
    const int* __restrict__ cnt, const float* __restrict__ att,
    const float* __restrict__ gat_b, const u16* __restrict__ x1b,
    const float* __restrict__ ln2_g, const float* __restrict__ ln2_b,
    float* __restrict__ out) {
    int bid = blockIdx.x;        // bid = n*4 + q
    int q = bid & 3;
    int n = bid >> 2;
    int tid = threadIdx.x;
    int gs = tid >> 4;
    int r = tid & 15;
    int h0 = ((r >> 2) << 5) + ((r & 3) << 3);  // head*32 + octet*8
    int g = q + 4 * gs;

    __shared__ int es[64], ss[64];
    int off = n * CSR_CAP, deg = cnt[n];
    int tot = deg + 1;  // + self-loop (last)

    float av[8], grv[8];
    {
        float4 a0 = *(const float4*)&att[h0];
        float4 a1 = *(const float4*)&att[h0 + 4];
        av[0] = a0.x; av[1] = a0.y; av[2] = a0.z; av[3] = a0.w;
        av[4] = a1.x; av[5] = a1.y; av[6] = a1.z; av[7] = a1.w;
        u32x4 g4 = *(const u32x4*)&gr[((size_t)g * N_NODES + n) * H_DIM + h0];
        grv[0] = bflo(g4.x); grv[1] = bfhi(g4.x); grv[2] = bflo(g4.y); grv[3] = bfhi(g4.y);
        grv[4] = bflo(g4.z); grv[5] = bfhi(g4.z); grv[6] = bflo(g4.w); grv[7] = bfhi(g4.w);
    }
    const u16* glg = gl + (size_t)g * N_NODES * H_DIM + h0;
    const u16* eeh = ee + h0;

    size_t ob = ((size_t)n * T_STEPS + g) * H_DIM + h0;
    u32x4 xv = __builtin_nontemporal_load((const u32x4*)&x1b[ob]);

    float m = -INFINITY, l = 0.f;
    float ac[8] = {0.f, 0.f, 0.f, 0.f, 0.f, 0.f, 0.f, 0.f};

    auto LDQ = [&](u32x4& G, u32x4& E, int idx) {
        int s_ = ss[idx], e_ = es[idx];
        G = *(const u32x4*)&glg[(size_t)s_ * H_DIM];
        E = __builtin_nontemporal_load((const u32x4*)&eeh[(size_t)e_ * H_DIM]);
    };
    auto PROC = [&](u32x4 gc, u32x4 ec) {
        float gvv[8];
        gvv[0] = bflo(gc.x); gvv[1] = bfhi(gc.x); gvv[2] = bflo(gc.y); gvv[3] = bfhi(gc.y);
        gvv[4] = bflo(gc.z); gvv[5] = bfhi(gc.z); gvv[6] = bflo(gc.w); gvv[7] = bfhi(gc.w);
        float evv[8];
        evv[0] = bflo(ec.x); evv[1] = bfhi(ec.x); evv[2] = bflo(ec.y); evv[3] = bfhi(ec.y);
        evv[4] = bflo(ec.z); evv[5] = bfhi(ec.z); evv[6] = bflo(ec.w); evv[7] = bfhi(ec.w);
        float p = 0.f;
#pragma unroll
        for (int j = 0; j < 8; ++j) {
            float sf = gvv[j] + grv[j] + evv[j];
            sf = fmaxf(sf, NEG_SLOPE * sf);  // leaky_relu for slope<1
            p = fmaf(sf, av[j], p);
        }
        p += __shfl_xor(p, 1);
        p += __shfl_xor(p, 2);
        // defer-max (T13): loads are hoisted by the explicit LDQ pipeline, so this
        // branch no longer blocks memory issue; fast path saves ~10 VALU/iter
        bool grow = p > m + 8.f;
        if (__any(grow)) {
            float mn = fmaxf(m, p);
            float sc = __expf(m - mn);
            float wq = __expf(p - mn);
            l = l * sc + wq;
#pragma unroll
            for (int j = 0; j < 8; ++j) ac[j] = ac[j] * sc + wq * gvv[j];
            m = mn;
        } else {
            float wq = __expf(p - m);
            l += wq;
#pragma unroll
            for (int j = 0; j < 8; ++j) ac[j] = fmaf(wq, gvv[j], ac[j]);
        }
    };

    for (int base = 0; base < tot; base += 64) {
        int c = min(64, tot - base);
        __syncthreads();
        if (tid < c) {
            int i = base + tid;
            int e = (i < deg) ? csr[off + i] : (E_EDGES + n);
            es[tid] = e;
            ss[tid] = (i < deg) ? src_arr[e] : n;
        }
        __syncthreads();
        int c1 = c - 1;
        u32x4 gA, eA, gB, eB, gC, eC, gD, eD;
        LDQ(gA, eA, 0);
        LDQ(gB, eB, min(1, c1));
        LDQ(gC, eC, min(2, c1));
        LDQ(gD, eD, min(3, c1));
        for (int i = 0; i < c; i += 4) {
            u32x4 g0 = gA, e0 = eA, g1 = gB, e1 = eB;
            u32x4 g2 = gC, e2 = eC, g3 = gD, e3 = eD;
            LDQ(gA, eA, min(i + 4, c1));
            LDQ(gB, eB, min(i + 5, c1));
            LDQ(gC, eC, min(i + 6, c1));
            LDQ(gD, eD, min(i + 7, c1));
            PROC(g0, e0);
            if (i + 1 < c) PROC(g1, e1);
            if (i + 2 < c) PROC(g2, e2);
            if (i + 3 < c) PROC(g3, e3);
        }
    }

    // epilogue: residual (bf16 x1) + LN2; reduce over the 16 lanes of this graph slot
    float linv = 1.0f / l;
    float4 gb0 = *(const float4*)&gat_b[h0];
    float4 gb1 = *(const float4*)&gat_b[h0 + 4];
    float xr[8];
    xr[0] = bflo(xv.x); xr[1] = bfhi(xv.x); xr[2] = bflo(xv.y); xr[3] = bfhi(xv.y);
    xr[4] = bflo(xv.z); xr[5] = bfhi(xv.z); xr[6] = bflo(xv.w); xr[7] = bfhi(xv.w);
    float gbv[8] = {gb0.x, gb0.y, gb0.z, gb0.w, gb1.x, gb1.y, gb1.z, gb1.w};
    float rv[8];
    float s1 = 0.f, s2v = 0.f;
#pragma unroll
    for (int j = 0; j < 8; ++j) {
        rv[j] = xr[j] + ac[j] * linv + gbv[j];
        s1 += rv[j];
        s2v += rv[j] * rv[j];
    }
#pragma unroll
    for (int mm = 1; mm < 16; mm <<= 1) {
        s1 += __shfl_xor(s1, mm);
        s2v += __shfl_xor(s2v, mm);
    }
    float mean = s1 * (1.f / 128.f);
    float var = s2v * (1.f / 128.f) - mean * mean;
    float rs = rsqrtf(var + LN_EPS);
    float4 g20 = *(const float4*)&ln2_g[h0];
    float4 g21 = *(const float4*)&ln2_g[h0 + 4];
    float4 b20 = *(const float4*)&ln2_b[h0];
    float4 b21 = *(const float4*)&ln2_b[h0 + 4];
    f32x4 o0, o1;
    o0.x = (rv[0] - mean) * rs * g20.x + b20.x;
    o0.y = (rv[1] - mean) * rs * g20.y + b20.y;
    o0.z = (rv[2] - mean) * rs * g20.z + b20.z;
    o0.w = (rv[3] - mean) * rs * g20.w + b20.w;
    o1.x = (rv[4] - mean) * rs * g21.x + b21.x;
    o1.y = (rv[5] - mean) * rs * g21.y + b21.y;
    o1.z = (rv[6] - mean) * rs * g21.z + b21.z;
    o1.w = (rv[7] - mean) * rs * g21.w + b21.w;
    __builtin_nontemporal_store(o0, (f32x4*)&out[ob]);
    __builtin_nontemporal_store(o1, (f32x4*)&out[ob + 4]);
}

extern "C" void kernel_launch(void* const* d_in, const int* in_sizes, int n_in,
                              void* d_out, int out_size, void* d_ws, size_t ws_size,
                              hipStream_t stream) {
    const float* x         = (const float*)d_in[0];
    const int*   ei        = (const int*)d_in[1];
    const float* edge_attr = (const float*)d_in[2];
    const float* conv_w    = (const float*)d_in[3];
    const float* conv_b    = (const float*)d_in[4];
    const float* ln1_g     = (const float*)d_in[5];
    const float* ln1_b     = (const float*)d_in[6];
    const float* Wl        = (const float*)d_in[7];
    const float* Wr        = (const float*)d_in[8];
    const float* We        = (const float*)d_in[9];
    const float* att       = (const float*)d_in[10];
    const float* gat_b     = (const float*)d_in[11];
    const float* ln2_g     = (const float*)d_in[12];
    const float* ln2_b     = (const float*)d_in[13];
    float* out = (float*)d_out;

    const int* src = ei;
    const int* dst = ei + E_EDGES;

    // workspace layout (all bf16 activations)
    u16* x1b    = (u16*)d_ws;                   // 4,096,000 bf16 [n][t][h]
    u16* glb    = x1b + 4096000;                // 4,096,000 bf16 [g][n][h]
    u16* grb    = glb + 4096000;                // 4,096,000 bf16 [g][n][h]
    u16* eeb    = grb + 4096000;                // 2,176,000 bf16
    int* cnt    = (int*)(eeb + 2176000);        // 1000
    int* csr    = cnt + 1000;                   // 128,000 (fixed-cap CSR [n][128])
    short* wc   = (short*)(csr + 128000);       // 49152 shorts (16B aligned)
    short* wg   = wc + 49152;                   // 32768 shorts

    k_prep<<<80, 1024, 0, stream>>>(conv_w, Wl, Wr, wc, wg);
    k_fuse<<<3000, 256, 0, stream>>>(x, wc, wg, conv_b, ln1_g, ln1_b, edge_attr, We,
                                     dst, csr, cnt, x1b, glb, grb, eeb);
    k_gat<<<4 * N_NODES, 128, 0, stream>>>(glb, grb, eeb, src, csr, cnt,
                                           att, gat_b, x1b, ln2_g, ln2_b, out);
}

// Round 17
// 73.007 us; speedup vs baseline: 1.0445x; 1.0445x over previous
//
#include <hip/hip_runtime.h>
#include <math.h>

#define N_NODES 1000
#define T_STEPS 32
#define H_DIM   128
#define E_EDGES 16000
#define ED_DIM  16
#define G_GRAPHS 32
#define EP_EDGES (E_EDGES + N_NODES)
#define NEG_SLOPE 0.2f
#define LN_EPS 1e-5f
#define CSR_CAP 128

typedef __attribute__((ext_vector_type(8))) short bf16x8;
typedef __attribute__((ext_vector_type(16))) float f32x16;
typedef __attribute__((ext_vector_type(4))) float f32x4;
typedef __attribute__((ext_vector_type(4))) unsigned u32x4;
typedef unsigned short u16;

__device__ inline short f2bf(float f) {  // RNE f32 -> bf16
    unsigned u = __float_as_uint(f);
    u = (u + 0x7FFFu + ((u >> 16) & 1u)) >> 16;
    return (short)u;
}
__device__ inline float bf2f(u16 u) { return __uint_as_float(((unsigned)u) << 16); }
__device__ inline float bflo(unsigned u) { return __uint_as_float(u << 16); }
__device__ inline float bfhi(unsigned u) { return __uint_as_float(u & 0xFFFF0000u); }

// ---------- L1: pack weights only (80 blocks) ----------
__global__ __launch_bounds__(1024) void k_prep(
    const float* __restrict__ conv_w, const float* __restrict__ Wl,
    const float* __restrict__ Wr, short* __restrict__ wc, short* __restrict__ wg) {
    int i = blockIdx.x * 1024 + threadIdx.x;  // 0..81919
    if (i < 4 * 24 * 64 * 8) {
        int r = i & 7, lane = (i >> 3) & 63;
        int t = i >> 9;
        int kstep = t % 24, ct = t / 24;
        int k = kstep >> 3, hs = kstep & 7;
        int hi = hs * 16 + ((lane >> 5) << 3) + r;
        int o = ct * 32 + (lane & 31);
        wc[i] = f2bf(conv_w[(o * H_DIM + hi) * 3 + k]);
    } else {
        int j = i - 4 * 24 * 64 * 8;  // < 32768
        int r = j & 7, lane = (j >> 3) & 63;
        int ks = (j >> 9) & 7, ct = j >> 12;
        int hi = ks * 16 + ((lane >> 5) << 3) + r;
        int o = ct * 32 + (lane & 31);
        wg[j] = f2bf(o < H_DIM ? Wl[hi * H_DIM + o] : Wr[hi * H_DIM + o - H_DIM]);
    }
}

// ---------- L2 fused: temporal (0-999) | CSR build+sort+loop_attr+self-ee (1000-1999)
//            | edge ee x16 (2000-2999). Static LDS ~18.5KB -> 8 blocks/CU ----------
__global__ __launch_bounds__(256) void k_fuse(
    const float* __restrict__ x, const short* __restrict__ wc, const short* __restrict__ wg,
    const float* __restrict__ conv_b, const float* __restrict__ ln1_g,
    const float* __restrict__ ln1_b, const float* __restrict__ edge_attr,
    const float* __restrict__ We, const int* __restrict__ dst,
    int* __restrict__ csr, int* __restrict__ cnt,
    u16* __restrict__ x1b, u16* __restrict__ gl, u16* __restrict__ gr,
    u16* __restrict__ ee) {
    __shared__ __align__(16) short xb[34 * 136];   // 9248 B; also gr-stage in epilogue
    __shared__ __align__(16) u16 yb[32 * 136];     // 8704 B; conv-out bf16; gl-stage in epilogue
    __shared__ int buf[CSR_CAP];
    __shared__ float laf[16];
    __shared__ int scnt;
    int b = blockIdx.x;
    int tid = threadIdx.x;

    if (b >= 2000) {  // ---- edge ee: 16 edges per block ----
        int e0 = (b - 2000) * 16 + (tid >> 7);
        int h = tid & 127;
#pragma unroll
        for (int k = 0; k < 16; k += 2) {
            int e = e0 + k;
            const float* ea = &edge_attr[e * ED_DIM];
            float acc = 0.f;
#pragma unroll
            for (int f = 0; f < ED_DIM; ++f) acc += ea[f] * We[f * H_DIM + h];
            __builtin_nontemporal_store((u16)f2bf(acc), &ee[(size_t)e * H_DIM + h]);
        }
        return;
    }
    if (b >= 1000) {  // ---- CSR build (scan dst) + sort + loop_attr + self-loop ee ----
        int n = b - 1000;
        if (tid == 0) scnt = 0;
        __syncthreads();
        const uint4* d4 = (const uint4*)dst;  // E_EDGES % 4 == 0
        for (int i = tid; i < E_EDGES / 4; i += 256) {
            uint4 v = d4[i];
            int e0 = i * 4;
            if ((int)v.x == n) { int s = atomicAdd(&scnt, 1); if (s < CSR_CAP) buf[s] = e0; }
            if ((int)v.y == n) { int s = atomicAdd(&scnt, 1); if (s < CSR_CAP) buf[s] = e0 + 1; }
            if ((int)v.z == n) { int s = atomicAdd(&scnt, 1); if (s < CSR_CAP) buf[s] = e0 + 2; }
            if ((int)v.w == n) { int s = atomicAdd(&scnt, 1); if (s < CSR_CAP) buf[s] = e0 + 3; }
        }
        __syncthreads();
        int deg = min(scnt, CSR_CAP);
        if (tid == 0) cnt[n] = deg;
        bool fast = (deg <= 64);
        if (fast) {
            if (tid < 64) {
                int v = (tid < deg) ? buf[tid] : 0x7FFFFFFF;
                int rank = 0;
#pragma unroll
                for (int j = 0; j < 64; ++j) {
                    int vj = __shfl(v, j);
                    rank += (vj < v) ? 1 : 0;
                }
                if (tid < deg) buf[rank] = v;
            }
        } else {
            if (tid == 0) {
                for (int i = 1; i < deg; ++i) {
                    int key = buf[i], j = i - 1;
                    while (j >= 0 && buf[j] > key) { buf[j + 1] = buf[j]; --j; }
                    buf[j + 1] = key;
                }
            }
        }
        __syncthreads();
        if (tid < deg) csr[n * CSR_CAP + tid] = buf[tid];
        if (tid < 64) {
            int q = tid >> 4, f = tid & 15;
            float a = 0.f;
            for (int i = q; i < deg; i += 4) a += edge_attr[buf[i] * ED_DIM + f];
            a += __shfl_xor(a, 16);
            a += __shfl_xor(a, 32);
            if (tid < 16) laf[tid] = a / fmaxf((float)deg, 1.0f);
        }
        __syncthreads();
        if (tid < H_DIM) {
            float acc = 0.f;
#pragma unroll
            for (int f = 0; f < ED_DIM; ++f) acc += laf[f] * We[f * H_DIM + tid];
            ee[(size_t)(E_EDGES + n) * H_DIM + tid] = (u16)f2bf(acc);
        }
        return;
    }

    // ---- temporal: conv (MFMA) + residual + LN1 + gl/gr (MFMA), bf16 outputs ----
    int n = b;
    int w = tid >> 6, lane = tid & 63;
    int arow = lane & 31;
    int aks = (lane >> 5) << 3;

    {
        const f32x4* xs4 = (const f32x4*)(x + (size_t)n * T_STEPS * H_DIM);
        for (int i4 = tid; i4 < T_STEPS * H_DIM / 4; i4 += 256) {
            f32x4 v = __builtin_nontemporal_load(&xs4[i4]);  // single-touch stream
            int t = i4 >> 5, h = (i4 * 4) & 127;
            uint2 pp;
            pp.x = (unsigned)(unsigned short)f2bf(v.x) | ((unsigned)(unsigned short)f2bf(v.y) << 16);
            pp.y = (unsigned)(unsigned short)f2bf(v.z) | ((unsigned)(unsigned short)f2bf(v.w) << 16);
            *(uint2*)&xb[(t + 1) * 136 + h] = pp;
        }
        if (tid < 68) {
            ((unsigned*)xb)[tid] = 0u;
            ((unsigned*)(xb + 33 * 136))[tid] = 0u;
        }
    }
    __syncthreads();

    f32x16 acc = {};
    for (int kk = 0; kk < 3; ++kk) {
#pragma unroll
        for (int hs = 0; hs < 8; ++hs) {
            int kstep = kk * 8 + hs;
            bf16x8 a = *(const bf16x8*)&xb[(arow + kk) * 136 + hs * 16 + aks];
            bf16x8 bb = *(const bf16x8*)&wc[((w * 24 + kstep) * 64 + lane) * 8];
            acc = __builtin_amdgcn_mfma_f32_32x32x16_bf16(a, bb, acc, 0, 0, 0);
        }
    }
    {
        int oc = w * 32 + (lane & 31);
        float cb = conv_b[oc];
#pragma unroll
        for (int r = 0; r < 16; ++r) {
            int t = (r & 3) + 8 * (r >> 2) + 4 * (lane >> 5);
            yb[t * 136 + oc] = (u16)f2bf(acc[r] + cb);  // bf16 staging (absmax-verified R16)
        }
    }
    __syncthreads();

    // residual from bf16 x (xb halo rows) + bf16 conv-out + LN1; reg-stage (WAR across waves)
    float rr0[8], rr1[8];
#pragma unroll
    for (int idx = 0; idx < 8; ++idx) {
        int t = w + idx * 4;
        rr0[idx] = bf2f((u16)xb[(t + 1) * 136 + lane]) + bf2f(yb[t * 136 + lane]);
        rr1[idx] = bf2f((u16)xb[(t + 1) * 136 + lane + 64]) + bf2f(yb[t * 136 + lane + 64]);
    }
    __syncthreads();
    float g0c = ln1_g[lane], g1c = ln1_g[lane + 64];
    float b0c = ln1_b[lane], b1c = ln1_b[lane + 64];
#pragma unroll
    for (int idx = 0; idx < 8; ++idx) {
        int t = w + idx * 4;
        float r0 = rr0[idx], r1 = rr1[idx];
        float s = r0 + r1, s2 = r0 * r0 + r1 * r1;
#pragma unroll
        for (int mm = 1; mm < 64; mm <<= 1) {
            s += __shfl_xor(s, mm);
            s2 += __shfl_xor(s2, mm);
        }
        float mean = s * (1.f / 128.f);
        float var = s2 * (1.f / 128.f) - mean * mean;
        float rs = rsqrtf(var + LN_EPS);
        float o0 = (r0 - mean) * rs * g0c + b0c;
        float o1 = (r1 - mean) * rs * g1c + b1c;
        xb[t * 136 + lane] = f2bf(o0);
        xb[t * 136 + lane + 64] = f2bf(o1);
    }
    __syncthreads();

    for (int c = tid; c < 512; c += 256) {
        int t = c >> 4, p = c & 15;
        u32x4 v = *(const u32x4*)&xb[t * 136 + p * 8];
        *(u32x4*)&x1b[((size_t)n * T_STEPS + t) * H_DIM + p * 8] = v;
    }

    f32x16 cl = {}, cr = {};
#pragma unroll
    for (int ks = 0; ks < 8; ++ks) {
        bf16x8 a = *(const bf16x8*)&xb[arow * 136 + ks * 16 + aks];
        bf16x8 b0 = *(const bf16x8*)&wg[(((2 * w) * 8 + ks) * 64 + lane) * 8];
        bf16x8 b1 = *(const bf16x8*)&wg[(((2 * w + 1) * 8 + ks) * 64 + lane) * 8];
        cl = __builtin_amdgcn_mfma_f32_32x32x16_bf16(a, b0, cl, 0, 0, 0);
        cr = __builtin_amdgcn_mfma_f32_32x32x16_bf16(a, b1, cr, 0, 0, 0);
    }
    // single-pass epilogue: gl staged into yb, gr staged into xb (xb's MFMA reads done)
    __syncthreads();
    {
        u16* st = (w >> 1) ? (u16*)xb : yb;   // waves 0,1 -> gl (yb); waves 2,3 -> gr (xb)
        int c0 = (w & 1) * 64 + (lane & 31);
#pragma unroll
        for (int r = 0; r < 16; ++r) {
            int t = (r & 3) + 8 * (r >> 2) + 4 * (lane >> 5);
            st[t * 136 + c0] = (u16)f2bf(cl[r]);
            st[t * 136 + c0 + 32] = (u16)f2bf(cr[r]);
        }
    }
    __syncthreads();
    {
        for (int c = tid; c < 1024; c += 256) {
            int m = c >> 9, t = (c >> 4) & 31, p = c & 15;
            const u16* st = m ? (const u16*)xb : yb;
            u32x4 v = *(const u32x4*)&st[t * 136 + p * 8];
            u16* d = m ? gr : gl;
            *(u32x4*)&d[((size_t)t * N_NODES + n) * H_DIM + p * 8] = v;
        }
    }
}

// ---------- GATv2: block=(n, 8 graphs q+4j); 4-deep pipelined gather, branchless softmax ----------
__global__ __launch_bounds__(128) void k_gat(
    const u16* __restrict__ gl, const u16* __restrict__ gr, const u16* __restrict__ ee,
    const int* __restrict__ src_arr, const int* __restrict__ csr,
    const int* __restrict__ cnt, const float* __restrict__ att,
    const float* __restrict__ gat_b, const u16* __restrict__ x1b,
    const float* __restrict__ ln2_g, const float* __restrict__ ln2_b,
    float* __restrict__ out) {
    int bid = blockIdx.x;        // bid = n*4 + q
    int q = bid & 3;
    int n = bid >> 2;
    int tid = threadIdx.x;
    int gs = tid >> 4;
    int r = tid & 15;
    int h0 = ((r >> 2) << 5) + ((r & 3) << 3);  // head*32 + octet*8
    int g = q + 4 * gs;

    __shared__ int es[64], ss[64];
    int off = n * CSR_CAP, deg = cnt[n];
    int tot = deg + 1;  // + self-loop (last)

    float av[8], grv[8];
    {
        float4 a0 = *(const float4*)&att[h0];
        float4 a1 = *(const float4*)&att[h0 + 4];
        av[0] = a0.x; av[1] = a0.y; av[2] = a0.z; av[3] = a0.w;
        av[4] = a1.x; av[5] = a1.y; av[6] = a1.z; av[7] = a1.w;
        u32x4 g4 = *(const u32x4*)&gr[((size_t)g * N_NODES + n) * H_DIM + h0];
        grv[0] = bflo(g4.x); grv[1] = bfhi(g4.x); grv[2] = bflo(g4.y); grv[3] = bfhi(g4.y);
        grv[4] = bflo(g4.z); grv[5] = bfhi(g4.z); grv[6] = bflo(g4.w); grv[7] = bfhi(g4.w);
    }
    const u16* glg = gl + (size_t)g * N_NODES * H_DIM + h0;
    const u16* eeh = ee + h0;

    size_t ob = ((size_t)n * T_STEPS + g) * H_DIM + h0;
    u32x4 xv = __builtin_nontemporal_load((const u32x4*)&x1b[ob]);

    float m = -INFINITY, l = 0.f;
    float ac[8] = {0.f, 0.f, 0.f, 0.f, 0.f, 0.f, 0.f, 0.f};

    auto LDQ = [&](u32x4& G, u32x4& E, int idx) {
        int s_ = ss[idx], e_ = es[idx];
        G = *(const u32x4*)&glg[(size_t)s_ * H_DIM];
        E = __builtin_nontemporal_load((const u32x4*)&eeh[(size_t)e_ * H_DIM]);
    };
    auto PROC = [&](u32x4 gc, u32x4 ec) {
        float gvv[8];
        gvv[0] = bflo(gc.x); gvv[1] = bfhi(gc.x); gvv[2] = bflo(gc.y); gvv[3] = bfhi(gc.y);
        gvv[4] = bflo(gc.z); gvv[5] = bfhi(gc.z); gvv[6] = bflo(gc.w); gvv[7] = bfhi(gc.w);
        float evv[8];
        evv[0] = bflo(ec.x); evv[1] = bfhi(ec.x); evv[2] = bflo(ec.y); evv[3] = bfhi(ec.y);
        evv[4] = bflo(ec.z); evv[5] = bfhi(ec.z); evv[6] = bflo(ec.w); evv[7] = bfhi(ec.w);
        float p = 0.f;
#pragma unroll
        for (int j = 0; j < 8; ++j) {
            float sf = gvv[j] + grv[j] + evv[j];
            sf = fmaxf(sf, NEG_SLOPE * sf);  // leaky_relu for slope<1
            p = fmaf(sf, av[j], p);
        }
        p += __shfl_xor(p, 1);
        p += __shfl_xor(p, 2);
        float mn = fmaxf(m, p);
        float sc = __expf(m - mn);   // ==1.0 exactly when p<=m
        float wq = __expf(p - mn);
        l = l * sc + wq;
#pragma unroll
        for (int j = 0; j < 8; ++j) ac[j] = ac[j] * sc + wq * gvv[j];
        m = mn;
    };

    for (int base = 0; base < tot; base += 64) {
        int c = min(64, tot - base);
        __syncthreads();
        if (tid < c) {
            int i = base + tid;
            int e = (i < deg) ? csr[off + i] : (E_EDGES + n);
            es[tid] = e;
            ss[tid] = (i < deg) ? src_arr[e] : n;
        }
        __syncthreads();
        int c1 = c - 1;
        u32x4 gA, eA, gB, eB, gC, eC, gD, eD;
        LDQ(gA, eA, 0);
        LDQ(gB, eB, min(1, c1));
        LDQ(gC, eC, min(2, c1));
        LDQ(gD, eD, min(3, c1));
        for (int i = 0; i < c; i += 4) {
            u32x4 g0 = gA, e0 = eA, g1 = gB, e1 = eB;
            u32x4 g2 = gC, e2 = eC, g3 = gD, e3 = eD;
            LDQ(gA, eA, min(i + 4, c1));
            LDQ(gB, eB, min(i + 5, c1));
            LDQ(gC, eC, min(i + 6, c1));
            LDQ(gD, eD, min(i + 7, c1));
            PROC(g0, e0);
            if (i + 1 < c) PROC(g1, e1);
            if (i + 2 < c) PROC(g2, e2);
            if (i + 3 < c) PROC(g3, e3);
        }
    }

    // epilogue: residual (bf16 x1) + LN2; reduce over the 16 lanes of this graph slot
    float linv = 1.0f / l;
    float4 gb0 = *(const float4*)&gat_b[h0];
    float4 gb1 = *(const float4*)&gat_b[h0 + 4];
    float xr[8];
    xr[0] = bflo(xv.x); xr[1] = bfhi(xv.x); xr[2] = bflo(xv.y); xr[3] = bfhi(xv.y);
    xr[4] = bflo(xv.z); xr[5] = bfhi(xv.z); xr[6] = bflo(xv.w); xr[7] = bfhi(xv.w);
    float gbv[8] = {gb0.x, gb0.y, gb0.z, gb0.w, gb1.x, gb1.y, gb1.z, gb1.w};
    float rv[8];
    float s1 = 0.f, s2v = 0.f;
#pragma unroll
    for (int j = 0; j < 8; ++j) {
        rv[j] = xr[j] + ac[j] * linv + gbv[j];
        s1 += rv[j];
        s2v += rv[j] * rv[j];
    }
#pragma unroll
    for (int mm = 1; mm < 16; mm <<= 1) {
        s1 += __shfl_xor(s1, mm);
        s2v += __shfl_xor(s2v, mm);
    }
    float mean = s1 * (1.f / 128.f);
    float var = s2v * (1.f / 128.f) - mean * mean;
    float rs = rsqrtf(var + LN_EPS);
    float4 g20 = *(const float4*)&ln2_g[h0];
    float4 g21 = *(const float4*)&ln2_g[h0 + 4];
    float4 b20 = *(const float4*)&ln2_b[h0];
    float4 b21 = *(const float4*)&ln2_b[h0 + 4];
    f32x4 o0, o1;
    o0.x = (rv[0] - mean) * rs * g20.x + b20.x;
    o0.y = (rv[1] - mean) * rs * g20.y + b20.y;
    o0.z = (rv[2] - mean) * rs * g20.z + b20.z;
    o0.w = (rv[3] - mean) * rs * g20.w + b20.w;
    o1.x = (rv[4] - mean) * rs * g21.x + b21.x;
    o1.y = (rv[5] - mean) * rs * g21.y + b21.y;
    o1.z = (rv[6] - mean) * rs * g21.z + b21.z;
    o1.w = (rv[7] - mean) * rs * g21.w + b21.w;
    __builtin_nontemporal_store(o0, (f32x4*)&out[ob]);
    __builtin_nontemporal_store(o1, (f32x4*)&out[ob + 4]);
}

extern "C" void kernel_launch(void* const* d_in, const int* in_sizes, int n_in,
                              void* d_out, int out_size, void* d_ws, size_t ws_size,
                              hipStream_t stream) {
    const float* x         = (const float*)d_in[0];
    const int*   ei        = (const int*)d_in[1];
    const float* edge_attr = (const float*)d_in[2];
    const float* conv_w    = (const float*)d_in[3];
    const float* conv_b    = (const float*)d_in[4];
    const float* ln1_g     = (const float*)d_in[5];
    const float* ln1_b     = (const float*)d_in[6];
    const float* Wl        = (const float*)d_in[7];
    const float* Wr        = (const float*)d_in[8];
    const float* We        = (const float*)d_in[9];
    const float* att       = (const float*)d_in[10];
    const float* gat_b     = (const float*)d_in[11];
    const float* ln2_g     = (const float*)d_in[12];
    const float* ln2_b     = (const float*)d_in[13];
    float* out = (float*)d_out;

    const int* src = ei;
    const int* dst = ei + E_EDGES;

    // workspace layout (all bf16 activations)
    u16* x1b    = (u16*)d_ws;                   // 4,096,000 bf16 [n][t][h]
    u16* glb    = x1b + 4096000;                // 4,096,000 bf16 [g][n][h]
    u16* grb    = glb + 4096000;                // 4,096,000 bf16 [g][n][h]
    u16* eeb    = grb + 4096000;                // 2,176,000 bf16
    int* cnt    = (int*)(eeb + 2176000);        // 1000
    int* csr    = cnt + 1000;                   // 128,000 (fixed-cap CSR [n][128])
    short* wc   = (short*)(csr + 128000);       // 49152 shorts (16B aligned)
    short* wg   = wc + 49152;                   // 32768 shorts

    k_prep<<<80, 1024, 0, stream>>>(conv_w, Wl, Wr, wc, wg);
    k_fuse<<<3000, 256, 0, stream>>>(x, wc, wg, conv_b, ln1_g, ln1_b, edge_attr, We,
                                     dst, csr, cnt, x1b, glb, grb, eeb);
    k_gat<<<4 * N_NODES, 128, 0, stream>>>(glb, grb, eeb, src, csr, cnt,
                                           att, gat_b, x1b, ln2_g, ln2_b, out);
}

// Round 18
// 72.925 us; speedup vs baseline: 1.0457x; 1.0011x over previous
//
#include <hip/hip_runtime.h>
#include <math.h>

#define N_NODES 1000
#define T_STEPS 32
#define H_DIM   128
#define E_EDGES 16000
#define ED_DIM  16
#define G_GRAPHS 32
#define EP_EDGES (E_EDGES + N_NODES)
#define NEG_SLOPE 0.2f
#define LN_EPS 1e-5f
#define CSR_CAP 128

typedef __attribute__((ext_vector_type(8))) short bf16x8;
typedef __attribute__((ext_vector_type(16))) float f32x16;
typedef __attribute__((ext_vector_type(4))) float f32x4;
typedef __attribute__((ext_vector_type(4))) unsigned u32x4;
typedef unsigned short u16;

__device__ inline short f2bf(float f) {  // RNE f32 -> bf16
    unsigned u = __float_as_uint(f);
    u = (u + 0x7FFFu + ((u >> 16) & 1u)) >> 16;
    return (short)u;
}
__device__ inline float bf2f(u16 u) { return __uint_as_float(((unsigned)u) << 16); }
__device__ inline float bflo(unsigned u) { return __uint_as_float(u << 16); }
__device__ inline float bfhi(unsigned u) { return __uint_as_float(u & 0xFFFF0000u); }

// ---------- L1: pack weights only (80 blocks) ----------
__global__ __launch_bounds__(1024) void k_prep(
    const float* __restrict__ conv_w, const float* __restrict__ Wl,
    const float* __restrict__ Wr, short* __restrict__ wc, short* __restrict__ wg) {
    int i = blockIdx.x * 1024 + threadIdx.x;  // 0..81919
    if (i < 4 * 24 * 64 * 8) {
        int r = i & 7, lane = (i >> 3) & 63;
        int t = i >> 9;
        int kstep = t % 24, ct = t / 24;
        int k = kstep >> 3, hs = kstep & 7;
        int hi = hs * 16 + ((lane >> 5) << 3) + r;
        int o = ct * 32 + (lane & 31);
        wc[i] = f2bf(conv_w[(o * H_DIM + hi) * 3 + k]);
    } else {
        int j = i - 4 * 24 * 64 * 8;  // < 32768
        int r = j & 7, lane = (j >> 3) & 63;
        int ks = (j >> 9) & 7, ct = j >> 12;
        int hi = ks * 16 + ((lane >> 5) << 3) + r;
        int o = ct * 32 + (lane & 31);
        wg[j] = f2bf(o < H_DIM ? Wl[hi * H_DIM + o] : Wr[hi * H_DIM + o - H_DIM]);
    }
}

// ---------- L2 fused: temporal (0-999) | CSR build+sort+loop_attr+self-ee (1000-1999)
//            | edge ee x16 (2000-2999). Static LDS ~18.5KB -> 8 blocks/CU ----------
__global__ __launch_bounds__(256) void k_fuse(
    const float* __restrict__ x, const short* __restrict__ wc, const short* __restrict__ wg,
    const float* __restrict__ conv_b, const float* __restrict__ ln1_g,
    const float* __restrict__ ln1_b, const float* __restrict__ edge_attr,
    const float* __restrict__ We, const int* __restrict__ dst,
    int* __restrict__ csr, int* __restrict__ cnt,
    u16* __restrict__ x1b, u16* __restrict__ gl, u16* __restrict__ gr,
    u16* __restrict__ ee) {
    __shared__ __align__(16) short xb[34 * 136];   // 9248 B; also gr-stage in epilogue
    __shared__ __align__(16) u16 yb[32 * 136];     // 8704 B; conv-out bf16; gl-stage in epilogue
    __shared__ int buf[CSR_CAP];
    __shared__ float laf[16];
    __shared__ int scnt;
    int b = blockIdx.x;
    int tid = threadIdx.x;

    if (b >= 2000) {  // ---- edge ee: 16 edges per block ----
        int e0 = (b - 2000) * 16 + (tid >> 7);
        int h = tid & 127;
#pragma unroll
        for (int k = 0; k < 16; k += 2) {
            int e = e0 + k;
            const float* ea = &edge_attr[e * ED_DIM];
            float acc = 0.f;
#pragma unroll
            for (int f = 0; f < ED_DIM; ++f) acc += ea[f] * We[f * H_DIM + h];
            __builtin_nontemporal_store((u16)f2bf(acc), &ee[(size_t)e * H_DIM + h]);
        }
        return;
    }
    if (b >= 1000) {  // ---- CSR build (scan dst) + sort + loop_attr + self-loop ee ----
        int n = b - 1000;
        if (tid == 0) scnt = 0;
        __syncthreads();
        const uint4* d4 = (const uint4*)dst;  // E_EDGES % 4 == 0
        for (int i = tid; i < E_EDGES / 4; i += 256) {
            uint4 v = d4[i];
            int e0 = i * 4;
            if ((int)v.x == n) { int s = atomicAdd(&scnt, 1); if (s < CSR_CAP) buf[s] = e0; }
            if ((int)v.y == n) { int s = atomicAdd(&scnt, 1); if (s < CSR_CAP) buf[s] = e0 + 1; }
            if ((int)v.z == n) { int s = atomicAdd(&scnt, 1); if (s < CSR_CAP) buf[s] = e0 + 2; }
            if ((int)v.w == n) { int s = atomicAdd(&scnt, 1); if (s < CSR_CAP) buf[s] = e0 + 3; }
        }
        __syncthreads();
        int deg = min(scnt, CSR_CAP);
        if (tid == 0) cnt[n] = deg;
        bool fast = (deg <= 64);
        if (fast) {
            if (tid < 64) {
                int v = (tid < deg) ? buf[tid] : 0x7FFFFFFF;
                int rank = 0;
#pragma unroll
                for (int j = 0; j < 64; ++j) {
                    int vj = __shfl(v, j);
                    rank += (vj < v) ? 1 : 0;
                }
                if (tid < deg) buf[rank] = v;
            }
        } else {
            if (tid == 0) {
                for (int i = 1; i < deg; ++i) {
                    int key = buf[i], j = i - 1;
                    while (j >= 0 && buf[j] > key) { buf[j + 1] = buf[j]; --j; }
                    buf[j + 1] = key;
                }
            }
        }
        __syncthreads();
        if (tid < deg) csr[n * CSR_CAP + tid] = buf[tid];
        if (tid < 64) {
            int q = tid >> 4, f = tid & 15;
            float a = 0.f;
            for (int i = q; i < deg; i += 4) a += edge_attr[buf[i] * ED_DIM + f];
            a += __shfl_xor(a, 16);
            a += __shfl_xor(a, 32);
            if (tid < 16) laf[tid] = a / fmaxf((float)deg, 1.0f);
        }
        __syncthreads();
        if (tid < H_DIM) {
            float acc = 0.f;
#pragma unroll
            for (int f = 0; f < ED_DIM; ++f) acc += laf[f] * We[f * H_DIM + tid];
            ee[(size_t)(E_EDGES + n) * H_DIM + tid] = (u16)f2bf(acc);
        }
        return;
    }

    // ---- temporal: conv (MFMA) + residual + LN1 + gl/gr (MFMA), bf16 outputs ----
    int n = b;
    int w = tid >> 6, lane = tid & 63;
    int arow = lane & 31;
    int aks = (lane >> 5) << 3;

    {
        const f32x4* xs4 = (const f32x4*)(x + (size_t)n * T_STEPS * H_DIM);
        for (int i4 = tid; i4 < T_STEPS * H_DIM / 4; i4 += 256) {
            f32x4 v = __builtin_nontemporal_load(&xs4[i4]);  // single-touch stream
            int t = i4 >> 5, h = (i4 * 4) & 127;
            uint2 pp;
            pp.x = (unsigned)(unsigned short)f2bf(v.x) | ((unsigned)(unsigned short)f2bf(v.y) << 16);
            pp.y = (unsigned)(unsigned short)f2bf(v.z) | ((unsigned)(unsigned short)f2bf(v.w) << 16);
            *(uint2*)&xb[(t + 1) * 136 + h] = pp;
        }
        if (tid < 68) {
            ((unsigned*)xb)[tid] = 0u;
            ((unsigned*)(xb + 33 * 136))[tid] = 0u;
        }
    }
    __syncthreads();

    f32x16 acc = {};
    for (int kk = 0; kk < 3; ++kk) {
#pragma unroll
        for (int hs = 0; hs < 8; ++hs) {
            int kstep = kk * 8 + hs;
            bf16x8 a = *(const bf16x8*)&xb[(arow + kk) * 136 + hs * 16 + aks];
            bf16x8 bb = *(const bf16x8*)&wc[((w * 24 + kstep) * 64 + lane) * 8];
            acc = __builtin_amdgcn_mfma_f32_32x32x16_bf16(a, bb, acc, 0, 0, 0);
        }
    }
    {
        int oc = w * 32 + (lane & 31);
        float cb = conv_b[oc];
#pragma unroll
        for (int r = 0; r < 16; ++r) {
            int t = (r & 3) + 8 * (r >> 2) + 4 * (lane >> 5);
            yb[t * 136 + oc] = (u16)f2bf(acc[r] + cb);  // bf16 staging (absmax-verified R16)
        }
    }
    __syncthreads();

    // residual from bf16 x (xb halo rows) + bf16 conv-out + LN1; reg-stage (WAR across waves)
    float rr0[8], rr1[8];
#pragma unroll
    for (int idx = 0; idx < 8; ++idx) {
        int t = w + idx * 4;
        rr0[idx] = bf2f((u16)xb[(t + 1) * 136 + lane]) + bf2f(yb[t * 136 + lane]);
        rr1[idx] = bf2f((u16)xb[(t + 1) * 136 + lane + 64]) + bf2f(yb[t * 136 + lane + 64]);
    }
    __syncthreads();
    float g0c = ln1_g[lane], g1c = ln1_g[lane + 64];
    float b0c = ln1_b[lane], b1c = ln1_b[lane + 64];
#pragma unroll
    for (int idx = 0; idx < 8; ++idx) {
        int t = w + idx * 4;
        float r0 = rr0[idx], r1 = rr1[idx];
        float s = r0 + r1, s2 = r0 * r0 + r1 * r1;
#pragma unroll
        for (int mm = 1; mm < 64; mm <<= 1) {
            s += __shfl_xor(s, mm);
            s2 += __shfl_xor(s2, mm);
        }
        float mean = s * (1.f / 128.f);
        float var = s2 * (1.f / 128.f) - mean * mean;
        float rs = rsqrtf(var + LN_EPS);
        float o0 = (r0 - mean) * rs * g0c + b0c;
        float o1 = (r1 - mean) * rs * g1c + b1c;
        xb[t * 136 + lane] = f2bf(o0);
        xb[t * 136 + lane + 64] = f2bf(o1);
    }
    __syncthreads();

    for (int c = tid; c < 512; c += 256) {
        int t = c >> 4, p = c & 15;
        u32x4 v = *(const u32x4*)&xb[t * 136 + p * 8];
        *(u32x4*)&x1b[((size_t)n * T_STEPS + t) * H_DIM + p * 8] = v;
    }

    f32x16 cl = {}, cr = {};
#pragma unroll
    for (int ks = 0; ks < 8; ++ks) {
        bf16x8 a = *(const bf16x8*)&xb[arow * 136 + ks * 16 + aks];
        bf16x8 b0 = *(const bf16x8*)&wg[(((2 * w) * 8 + ks) * 64 + lane) * 8];
        bf16x8 b1 = *(const bf16x8*)&wg[(((2 * w + 1) * 8 + ks) * 64 + lane) * 8];
        cl = __builtin_amdgcn_mfma_f32_32x32x16_bf16(a, b0, cl, 0, 0, 0);
        cr = __builtin_amdgcn_mfma_f32_32x32x16_bf16(a, b1, cr, 0, 0, 0);
    }
    // single-pass epilogue: gl staged into yb, gr staged into xb (xb's MFMA reads done)
    __syncthreads();
    {
        u16* st = (w >> 1) ? (u16*)xb : yb;   // waves 0,1 -> gl (yb); waves 2,3 -> gr (xb)
        int c0 = (w & 1) * 64 + (lane & 31);
#pragma unroll
        for (int r = 0; r < 16; ++r) {
            int t = (r & 3) + 8 * (r >> 2) + 4 * (lane >> 5);
            st[t * 136 + c0] = (u16)f2bf(cl[r]);
            st[t * 136 + c0 + 32] = (u16)f2bf(cr[r]);
        }
    }
    __syncthreads();
    {
        for (int c = tid; c < 1024; c += 256) {
            int m = c >> 9, t = (c >> 4) & 31, p = c & 15;
            const u16* st = m ? (const u16*)xb : yb;
            u32x4 v = *(const u32x4*)&st[t * 136 + p * 8];
            u16* d = m ? gr : gl;
            *(u32x4*)&d[((size_t)t * N_NODES + n) * H_DIM + p * 8] = v;
        }
    }
}

// ---------- GATv2: block=(n, 8 graphs q+4j); barrier-free wave-local index staging
//            (registers + shfl broadcast), 4-deep pipelined gather, branchless softmax ----------
__global__ __launch_bounds__(128) void k_gat(
    const u16* __restrict__ gl, const u16* __restrict__ gr, const u16* __restrict__ ee,
    const int* __restrict__ src_arr, const int* __restrict__ csr,
    const int* __restrict__ cnt, const float* __restrict__ att,
    const float* __restrict__ gat_b, const u16* __restrict__ x1b,
    const float* __restrict__ ln2_g, const float* __restrict__ ln2_b,
    float* __restrict__ out) {
    int bid = blockIdx.x;        // bid = n*4 + q
    int q = bid & 3;
    int n = bid >> 2;
    int tid = threadIdx.x;
    int lane = tid & 63;         // lane within wave
    int gs = tid >> 4;
    int r = tid & 15;
    int h0 = ((r >> 2) << 5) + ((r & 3) << 3);  // head*32 + octet*8
    int g = q + 4 * gs;

    int off = n * CSR_CAP, deg = cnt[n];
    int tot = deg + 1;  // + self-loop (last)

    float av[8], grv[8];
    {
        float4 a0 = *(const float4*)&att[h0];
        float4 a1 = *(const float4*)&att[h0 + 4];
        av[0] = a0.x; av[1] = a0.y; av[2] = a0.z; av[3] = a0.w;
        av[4] = a1.x; av[5] = a1.y; av[6] = a1.z; av[7] = a1.w;
        u32x4 g4 = *(const u32x4*)&gr[((size_t)g * N_NODES + n) * H_DIM + h0];
        grv[0] = bflo(g4.x); grv[1] = bfhi(g4.x); grv[2] = bflo(g4.y); grv[3] = bfhi(g4.y);
        grv[4] = bflo(g4.z); grv[5] = bfhi(g4.z); grv[6] = bflo(g4.w); grv[7] = bfhi(g4.w);
    }
    const u16* glg = gl + (size_t)g * N_NODES * H_DIM + h0;
    const u16* eeh = ee + h0;

    size_t ob = ((size_t)n * T_STEPS + g) * H_DIM + h0;
    u32x4 xv = __builtin_nontemporal_load((const u32x4*)&x1b[ob]);

    float m = -INFINITY, l = 0.f;
    float ac[8] = {0.f, 0.f, 0.f, 0.f, 0.f, 0.f, 0.f, 0.f};

    auto PROC = [&](u32x4 gc, u32x4 ec) {
        float gvv[8];
        gvv[0] = bflo(gc.x); gvv[1] = bfhi(gc.x); gvv[2] = bflo(gc.y); gvv[3] = bfhi(gc.y);
        gvv[4] = bflo(gc.z); gvv[5] = bfhi(gc.z); gvv[6] = bflo(gc.w); gvv[7] = bfhi(gc.w);
        float evv[8];
        evv[0] = bflo(ec.x); evv[1] = bfhi(ec.x); evv[2] = bflo(ec.y); evv[3] = bfhi(ec.y);
        evv[4] = bflo(ec.z); evv[5] = bfhi(ec.z); evv[6] = bflo(ec.w); evv[7] = bfhi(ec.w);
        float p = 0.f;
#pragma unroll
        for (int j = 0; j < 8; ++j) {
            float sf = gvv[j] + grv[j] + evv[j];
            sf = fmaxf(sf, NEG_SLOPE * sf);  // leaky_relu for slope<1
            p = fmaf(sf, av[j], p);
        }
        p += __shfl_xor(p, 1);
        p += __shfl_xor(p, 2);
        float mn = fmaxf(m, p);
        float sc = __expf(m - mn);   // ==1.0 exactly when p<=m
        float wq = __expf(p - mn);
        l = l * sc + wq;
#pragma unroll
        for (int j = 0; j < 8; ++j) ac[j] = ac[j] * sc + wq * gvv[j];
        m = mn;
    };

    for (int base = 0; base < tot; base += 64) {
        int c = min(64, tot - base);
        // wave-local index staging: lane i holds edge base+i (coalesced, no LDS, no barrier)
        int i_ = base + lane;
        int e_reg = (i_ < deg) ? csr[off + i_] : (E_EDGES + n);
        int s_reg = (i_ < deg) ? src_arr[e_reg] : n;

        auto LDQ = [&](u32x4& G, u32x4& E, int idx) {
            int e_ = __shfl(e_reg, idx);
            int s_ = __shfl(s_reg, idx);
            G = *(const u32x4*)&glg[(size_t)s_ * H_DIM];
            E = __builtin_nontemporal_load((const u32x4*)&eeh[(size_t)e_ * H_DIM]);
        };

        int c1 = c - 1;
        u32x4 gA, eA, gB, eB, gC, eC, gD, eD;
        LDQ(gA, eA, 0);
        LDQ(gB, eB, min(1, c1));
        LDQ(gC, eC, min(2, c1));
        LDQ(gD, eD, min(3, c1));
        for (int i = 0; i < c; i += 4) {
            u32x4 g0 = gA, e0 = eA, g1 = gB, e1 = eB;
            u32x4 g2 = gC, e2 = eC, g3 = gD, e3 = eD;
            LDQ(gA, eA, min(i + 4, c1));
            LDQ(gB, eB, min(i + 5, c1));
            LDQ(gC, eC, min(i + 6, c1));
            LDQ(gD, eD, min(i + 7, c1));
            PROC(g0, e0);
            if (i + 1 < c) PROC(g1, e1);
            if (i + 2 < c) PROC(g2, e2);
            if (i + 3 < c) PROC(g3, e3);
        }
    }

    // epilogue: residual (bf16 x1) + LN2; reduce over the 16 lanes of this graph slot
    float linv = 1.0f / l;
    float4 gb0 = *(const float4*)&gat_b[h0];
    float4 gb1 = *(const float4*)&gat_b[h0 + 4];
    float xr[8];
    xr[0] = bflo(xv.x); xr[1] = bfhi(xv.x); xr[2] = bflo(xv.y); xr[3] = bfhi(xv.y);
    xr[4] = bflo(xv.z); xr[5] = bfhi(xv.z); xr[6] = bflo(xv.w); xr[7] = bfhi(xv.w);
    float gbv[8] = {gb0.x, gb0.y, gb0.z, gb0.w, gb1.x, gb1.y, gb1.z, gb1.w};
    float rv[8];
    float s1 = 0.f, s2v = 0.f;
#pragma unroll
    for (int j = 0; j < 8; ++j) {
        rv[j] = xr[j] + ac[j] * linv + gbv[j];
        s1 += rv[j];
        s2v += rv[j] * rv[j];
    }
#pragma unroll
    for (int mm = 1; mm < 16; mm <<= 1) {
        s1 += __shfl_xor(s1, mm);
        s2v += __shfl_xor(s2v, mm);
    }
    float mean = s1 * (1.f / 128.f);
    float var = s2v * (1.f / 128.f) - mean * mean;
    float rs = rsqrtf(var + LN_EPS);
    float4 g20 = *(const float4*)&ln2_g[h0];
    float4 g21 = *(const float4*)&ln2_g[h0 + 4];
    float4 b20 = *(const float4*)&ln2_b[h0];
    float4 b21 = *(const float4*)&ln2_b[h0 + 4];
    f32x4 o0, o1;
    o0.x = (rv[0] - mean) * rs * g20.x + b20.x;
    o0.y = (rv[1] - mean) * rs * g20.y + b20.y;
    o0.z = (rv[2] - mean) * rs * g20.z + b20.z;
    o0.w = (rv[3] - mean) * rs * g20.w + b20.w;
    o1.x = (rv[4] - mean) * rs * g21.x + b21.x;
    o1.y = (rv[5] - mean) * rs * g21.y + b21.y;
    o1.z = (rv[6] - mean) * rs * g21.z + b21.z;
    o1.w = (rv[7] - mean) * rs * g21.w + b21.w;
    __builtin_nontemporal_store(o0, (f32x4*)&out[ob]);
    __builtin_nontemporal_store(o1, (f32x4*)&out[ob + 4]);
}

extern "C" void kernel_launch(void* const* d_in, const int* in_sizes, int n_in,
                              void* d_out, int out_size, void* d_ws, size_t ws_size,
                              hipStream_t stream) {
    const float* x         = (const float*)d_in[0];
    const int*   ei        = (const int*)d_in[1];
    const float* edge_attr = (const float*)d_in[2];
    const float* conv_w    = (const float*)d_in[3];
    const float* conv_b    = (const float*)d_in[4];
    const float* ln1_g     = (const float*)d_in[5];
    const float* ln1_b     = (const float*)d_in[6];
    const float* Wl        = (const float*)d_in[7];
    const float* Wr        = (const float*)d_in[8];
    const float* We        = (const float*)d_in[9];
    const float* att       = (const float*)d_in[10];
    const float* gat_b     = (const float*)d_in[11];
    const float* ln2_g     = (const float*)d_in[12];
    const float* ln2_b     = (const float*)d_in[13];
    float* out = (float*)d_out;

    const int* src = ei;
    const int* dst = ei + E_EDGES;

    // workspace layout (all bf16 activations)
    u16* x1b    = (u16*)d_ws;                   // 4,096,000 bf16 [n][t][h]
    u16* glb    = x1b + 4096000;                // 4,096,000 bf16 [g][n][h]
    u16* grb    = glb + 4096000;                // 4,096,000 bf16 [g][n][h]
    u16* eeb    = grb + 4096000;                // 2,176,000 bf16
    int* cnt    = (int*)(eeb + 2176000);        // 1000
    int* csr    = cnt + 1000;                   // 128,000 (fixed-cap CSR [n][128])
    short* wc   = (short*)(csr + 128000);       // 49152 shorts (16B aligned)
    short* wg   = wc + 49152;                   // 32768 shorts

    k_prep<<<80, 1024, 0, stream>>>(conv_w, Wl, Wr, wc, wg);
    k_fuse<<<3000, 256, 0, stream>>>(x, wc, wg, conv_b, ln1_g, ln1_b, edge_attr, We,
                                     dst, csr, cnt, x1b, glb, grb, eeb);
    k_gat<<<4 * N_NODES, 128, 0, stream>>>(glb, grb, eeb, src, csr, cnt,
                                           att, gat_b, x1b, ln2_g, ln2_b, out);
}